// Round 17
// baseline (93.979 us; speedup 1.0000x reference)
//
#include <hip/hip_runtime.h>
#include <hip/hip_bf16.h>

#define BQ   2
#define NH   12
#define SEQ  2048
#define DIM  64
#define EXQ  64   // end_x (both grids equal -> resample is identity)

#define TENSOR_ELEMS ((size_t)BQ * NH * SEQ * DIM)   // 3,145,728 bf16 each
#define ROPE_BLOCKS  6144                             // 2*BQ*NH*SEQ*16 / 256
#define PERS_BLOCKS  512                              // 2 blocks/CU exact
#define TILES_PER_BLOCK 12                            // 512*12 = 6144 tiles

typedef __attribute__((ext_vector_type(8))) short short8;
typedef __attribute__((ext_vector_type(4))) float f32x4;

static __device__ __forceinline__ unsigned int pk2bf(float lo, float hi) {
    union { float f; unsigned int u; } a, b; a.f = lo; b.f = hi;
    unsigned int rl = (a.u + 0x7fffu + ((a.u >> 16) & 1u)) >> 16;  // RNE
    unsigned int rh = (b.u + 0x7fffu + ((b.u >> 16) & 1u)) >> 16;
    return (rh << 16) | (rl & 0xffffu);
}

// barrier that does NOT drain vmcnt (plain __syncthreads emits vmcnt(0),
// which would stall on our fire-and-forget store stream)
static __device__ __forceinline__ void wg_barrier_lds() {
    asm volatile("s_waitcnt lgkmcnt(0)" ::: "memory");
    __builtin_amdgcn_s_barrier();
}

// ---- Phase 1: RoPE-rotate q,b -> bf16 ws (fast HW trig) --------------------
// ws layout: xq bf16[TENSOR_ELEMS] | xb bf16[TENSOR_ELEMS]
__global__ __launch_bounds__(256)
void rope_kernel(const float* __restrict__ qin,
                 const float* __restrict__ bin,
                 const float* __restrict__ freqs,   // [2, NH, 16]
                 unsigned int* __restrict__ ws_u32)
{
    int t  = blockIdx.x * 256 + threadIdx.x;
    int p4 = t & 15;                 // quad of elements (2 pairs)
    int n  = (t >> 4) & (SEQ - 1);
    int rest = t >> 15;              // (tensor*BQ+b)*NH + h
    int h    = rest % NH;
    int tb   = rest / NH;
    int tensor = tb >> 1;
    int b      = tb & 1;

    float tx = (float)(n & (EXQ - 1));
    float ty = (float)(n >> 6);

    int pr0 = 2 * p4;                // pair indices pr0, pr0+1
    float f0, f1;
    if (p4 < 8) {
        f0 = freqs[h * 16 + pr0] * tx;
        f1 = freqs[h * 16 + pr0 + 1] * tx;
    } else {
        f0 = freqs[NH * 16 + h * 16 + (pr0 - 16)] * ty;
        f1 = freqs[NH * 16 + h * 16 + (pr0 - 15)] * ty;
    }

    const float* src = tensor ? bin : qin;
    size_t off = ((size_t)(b * NH + h) * SEQ + n) * DIM + 4 * p4;
    float4 v = *reinterpret_cast<const float4*>(src + off);

    float s0 = __sinf(f0), c0 = __cosf(f0);   // v_sin/v_cos fast path
    float s1 = __sinf(f1), c1 = __cosf(f1);

    float o0 = v.x * c0 - v.y * s0;
    float o1 = v.x * s0 + v.y * c0;
    float o2 = v.z * c1 - v.w * s1;
    float o3 = v.z * s1 + v.w * c1;

    uint2 packed;
    packed.x = pk2bf(o0, o1);
    packed.y = pk2bf(o2, o3);
    size_t uidx = (size_t)tensor * (TENSOR_ELEMS / 2) + (off >> 1);
    *reinterpret_cast<uint2*>(ws_u32 + uidx) = packed;
}

// ---- Phase 2: persistent 64x256-tile MFMA GEMM + fused decay ---------------
// A/B vs R16 (single variable: tile aspect): 64x256 instead of 128x128, so
// the LDS drain emits ONE FULL 1 KB contiguous output row per wave-instr
// (matching the 6.9 TB/s fill kernel's burst shape) instead of 2x512 B.
// Per-wave geometry identical (64x64 sub-tile, acc[4][4], same frag counts,
// same 7-window decay with d=j-i+3; dy = tcol*4+wave-trow wave-uniform).
// Iteration-major mapping (g = t*512+blk): 2 heads/iter, ~1 MB working set,
// A panels shared by 8 concurrent blocks, B by 32. 64 KB LDS stage (XOR
// swizzle), plain f32x4 stores, lgkm-only barriers, prefetch-before-stores.
__global__ __launch_bounds__(256, 2)
void gemm_delta_kernel(const unsigned short* __restrict__ ws,
                       const float* __restrict__ weight,
                       float* __restrict__ out)
{
    __shared__ float lds[64 * 256];       // 64 KB stage (64 rows x 1 KB)

    const int lane = threadIdx.x & 63;
    const int wave = threadIdx.x >> 6;
    const int r16  = lane & 15;
    const int kg   = lane >> 4;

    const unsigned short* xq = ws;
    const unsigned short* xb = ws + TENSOR_ELEMS;

    short8 afr[2][4], bfr[2][4];

    // ---- load fragments for tile g ----
    // tile: trow = (g&255)>>3 (64-row panel), tcol = g&7 (256-col panel)
    auto load_frags = [&](int g) {
        int bh = g >> 8, rem = g & 255;
        int trow = rem >> 3, tcol = rem & 7;
        const size_t base = (size_t)bh * SEQ * DIM;
        int row0 = trow * 64;                    // shared by all 4 waves
        int col0 = tcol * 256 + wave * 64;       // per-wave 64-col slice
#pragma unroll
        for (int kk = 0; kk < 2; ++kk)
#pragma unroll
            for (int i = 0; i < 4; ++i) {
                int arw = row0 + i * 16 + r16;
                int bcl = col0 + i * 16 + r16;
                afr[kk][i] = *reinterpret_cast<const short8*>(
                    xq + base + (size_t)arw * DIM + kk * 32 + kg * 8);
                bfr[kk][i] = *reinterpret_cast<const short8*>(
                    xb + base + (size_t)bcl * DIM + kk * 32 + kg * 8);
            }
    };

    load_frags(blockIdx.x);

    for (int t = 0; t < TILES_PER_BLOCK; ++t) {
        const int g    = t * PERS_BLOCKS + blockIdx.x;   // iteration-major
        const int bh   = g >> 8, rem = g & 255;
        const int trow = rem >> 3, tcol = rem & 7;
        const int h    = bh % NH;
        const int brow0 = trow * 64, bcol0 = tcol * 256;

        // ---- MFMA (swapped operands -> lane holds 4 consecutive cols) ----
        f32x4 acc[4][4];
#pragma unroll
        for (int i = 0; i < 4; ++i)
#pragma unroll
            for (int j = 0; j < 4; ++j)
                acc[i][j] = (f32x4){0.f, 0.f, 0.f, 0.f};
#pragma unroll
        for (int kk = 0; kk < 2; ++kk)
#pragma unroll
            for (int i = 0; i < 4; ++i)
#pragma unroll
                for (int j = 0; j < 4; ++j)
                    acc[i][j] = __builtin_amdgcn_mfma_f32_16x16x32_bf16(
                        bfr[kk][j], afr[kk][i], acc[i][j], 0, 0, 0);

        // ---- in-register decay: 7 shared windows T[d], d = j-i+3 ----
        // dx = (j-i)*16 + kg*4 + w - r16 (identical to R16); dy wave-uniform
        {
            float w  = weight[h];
            float lw = w > 0.f ? w : 0.01f * w;
            float scale = -lw * 1.44269504088896f;
            float fdy = (float)(tcol * 4 + wave - trow);
            float dy2 = fdy * fdy;
            f32x4 T[7];
#pragma unroll
            for (int d = 0; d < 7; ++d) {
                float dx0 = (float)((d - 3) * 16 + kg * 4 - r16);
#pragma unroll
                for (int w_ = 0; w_ < 4; ++w_) {
                    float dx = dx0 + (float)w_;
                    float dist = __builtin_amdgcn_sqrtf(dx * dx + dy2);
                    T[d][w_] = __builtin_amdgcn_exp2f(scale * dist);
                }
            }
#pragma unroll
            for (int i = 0; i < 4; ++i)
#pragma unroll
                for (int j = 0; j < 4; ++j)
                    acc[i][j] *= T[j - i + 3];
        }

        // ---- prefetch next tile's fragments BEFORE this tile's stores ----
        if (t + 1 < TILES_PER_BLOCK)
            load_frags((t + 1) * PERS_BLOCKS + blockIdx.x);
        __builtin_amdgcn_sched_barrier(0);   // keep loads above the stores

        // ---- stage to LDS (swizzled; 16B slot index 0..63 per row) ----
        wg_barrier_lds();                    // prev drain reads complete
#pragma unroll
        for (int i = 0; i < 4; ++i) {
            int lrow = i * 16 + r16;                 // 0..63
#pragma unroll
            for (int j = 0; j < 4; ++j) {
                int slot = (wave * 16 + j * 4 + kg) ^ (lrow & 7);
                *reinterpret_cast<f32x4*>(&lds[lrow * 256 + slot * 4]) = acc[i][j];
            }
        }
        wg_barrier_lds();                    // stage visible to all waves

        // ---- drain: 16 instrs/wave, each ONE FULL 1 KB contiguous row ----
        const size_t obase = (size_t)bh * SEQ * SEQ;
#pragma unroll
        for (int tI = 0; tI < 16; ++tI) {
            int lr = wave * 16 + tI;                 // 0..63
            int slot = lane ^ (lr & 7);
            f32x4 v = *reinterpret_cast<const f32x4*>(&lds[lr * 256 + slot * 4]);
            float* op = out + obase + (size_t)(brow0 + lr) * SEQ + bcol0 + lane * 4;
            *reinterpret_cast<f32x4*>(op) = v;       // plain store
        }
    }
}

extern "C" void kernel_launch(void* const* d_in, const int* in_sizes, int n_in,
                              void* d_out, int out_size, void* d_ws, size_t ws_size,
                              hipStream_t stream) {
    const float* q  = (const float*)d_in[0];
    const float* b  = (const float*)d_in[1];
    const float* fr = (const float*)d_in[2];
    const float* wt = (const float*)d_in[3];
    float* out = (float*)d_out;

    const size_t need = 2 * TENSOR_ELEMS * sizeof(unsigned short);
    if (ws_size < need) return;

    rope_kernel<<<ROPE_BLOCKS, 256, 0, stream>>>(q, b, fr, (unsigned int*)d_ws);

    gemm_delta_kernel<<<PERS_BLOCKS, 256, 0, stream>>>(
        (const unsigned short*)d_ws, wt, out);
}

// Round 18
// 92.310 us; speedup vs baseline: 1.0181x; 1.0181x over previous
//
#include <hip/hip_runtime.h>
#include <hip/hip_bf16.h>

#define BQ   2
#define NH   12
#define SEQ  2048
#define DIM  64
#define EXQ  64   // end_x (both grids equal -> resample is identity)

#define TENSOR_ELEMS ((size_t)BQ * NH * SEQ * DIM)   // 3,145,728 bf16 each
#define ROPE_BLOCKS  6144                             // 2*BQ*NH*SEQ*16 / 256
#define PERS_BLOCKS  512                              // 2 blocks/CU exact
#define TILES_PER_BLOCK 12                            // 512*12 = 6144 tiles

typedef __attribute__((ext_vector_type(8))) short short8;
typedef __attribute__((ext_vector_type(4))) float f32x4;

static __device__ __forceinline__ unsigned int pk2bf(float lo, float hi) {
    union { float f; unsigned int u; } a, b; a.f = lo; b.f = hi;
    unsigned int rl = (a.u + 0x7fffu + ((a.u >> 16) & 1u)) >> 16;  // RNE
    unsigned int rh = (b.u + 0x7fffu + ((b.u >> 16) & 1u)) >> 16;
    return (rh << 16) | (rl & 0xffffu);
}

// barrier that does NOT drain vmcnt (plain __syncthreads emits vmcnt(0),
// which would stall on our fire-and-forget store stream)
static __device__ __forceinline__ void wg_barrier_lds() {
    asm volatile("s_waitcnt lgkmcnt(0)" ::: "memory");
    __builtin_amdgcn_s_barrier();
}

// ---- Phase 1: RoPE-rotate q,b -> bf16 ws (fast HW trig) --------------------
// ws layout: xq bf16[TENSOR_ELEMS] | xb bf16[TENSOR_ELEMS]
__global__ __launch_bounds__(256)
void rope_kernel(const float* __restrict__ qin,
                 const float* __restrict__ bin,
                 const float* __restrict__ freqs,   // [2, NH, 16]
                 unsigned int* __restrict__ ws_u32)
{
    int t  = blockIdx.x * 256 + threadIdx.x;
    int p4 = t & 15;                 // quad of elements (2 pairs)
    int n  = (t >> 4) & (SEQ - 1);
    int rest = t >> 15;              // (tensor*BQ+b)*NH + h
    int h    = rest % NH;
    int tb   = rest / NH;
    int tensor = tb >> 1;
    int b      = tb & 1;

    float tx = (float)(n & (EXQ - 1));
    float ty = (float)(n >> 6);

    int pr0 = 2 * p4;                // pair indices pr0, pr0+1
    float f0, f1;
    if (p4 < 8) {
        f0 = freqs[h * 16 + pr0] * tx;
        f1 = freqs[h * 16 + pr0 + 1] * tx;
    } else {
        f0 = freqs[NH * 16 + h * 16 + (pr0 - 16)] * ty;
        f1 = freqs[NH * 16 + h * 16 + (pr0 - 15)] * ty;
    }

    const float* src = tensor ? bin : qin;
    size_t off = ((size_t)(b * NH + h) * SEQ + n) * DIM + 4 * p4;
    float4 v = *reinterpret_cast<const float4*>(src + off);

    float s0 = __sinf(f0), c0 = __cosf(f0);   // v_sin/v_cos fast path
    float s1 = __sinf(f1), c1 = __cosf(f1);

    float o0 = v.x * c0 - v.y * s0;
    float o1 = v.x * s0 + v.y * c0;
    float o2 = v.z * c1 - v.w * s1;
    float o3 = v.z * s1 + v.w * c1;

    uint2 packed;
    packed.x = pk2bf(o0, o1);
    packed.y = pk2bf(o2, o3);
    size_t uidx = (size_t)tensor * (TENSOR_ELEMS / 2) + (off >> 1);
    *reinterpret_cast<uint2*>(ws_u32 + uidx) = packed;
}

// ---- Phase 2: persistent-block 128x128 MFMA GEMM + fused decay -------------
// ITERATION-MAJOR tile mapping: g = iter*512 + blockIdx. All 512 co-resident
// blocks process the same 2 heads per iteration, so each A/B panel is read by
// its 16 sharers CONCURRENTLY (~1 MB working set/iter -> L2/L3-resident) and
// HBM re-read traffic collapses to one 12.6 MB pass. Per tile: MFMA (swapped
// operands -> lane holds 4 consecutive cols), in-register decay via 7 (j-i)
// windows (raw v_sqrt/v_exp), 64 KB LDS transpose stage (XOR swizzle),
// lane-contiguous plain f32x4 stores, lgkm-only barriers,
// prefetch-before-stores.
__global__ __launch_bounds__(256, 2)
void gemm_delta_kernel(const unsigned short* __restrict__ ws,
                       const float* __restrict__ weight,
                       float* __restrict__ out)
{
    __shared__ float lds[128 * 128];      // 64 KB stage

    const int lane = threadIdx.x & 63;
    const int wave = threadIdx.x >> 6;
    const int wr   = wave >> 1, wc = wave & 1;
    const int r16  = lane & 15;
    const int kg   = lane >> 4;
    const int c32  = lane & 31;

    const unsigned short* xq = ws;
    const unsigned short* xb = ws + TENSOR_ELEMS;

    short8 afr[2][4], bfr[2][4];

    // ---- load fragments for tile g ----
    auto load_frags = [&](int g) {
        int bh = g >> 8, rem = g & 255;
        int trow = rem >> 4, tcol = rem & 15;
        const size_t base = (size_t)bh * SEQ * DIM;
        int row0 = trow * 128 + wr * 64;
        int col0 = tcol * 128 + wc * 64;
#pragma unroll
        for (int kk = 0; kk < 2; ++kk)
#pragma unroll
            for (int i = 0; i < 4; ++i) {
                int arw = row0 + i * 16 + r16;
                int bcl = col0 + i * 16 + r16;
                afr[kk][i] = *reinterpret_cast<const short8*>(
                    xq + base + (size_t)arw * DIM + kk * 32 + kg * 8);
                bfr[kk][i] = *reinterpret_cast<const short8*>(
                    xb + base + (size_t)bcl * DIM + kk * 32 + kg * 8);
            }
    };

    load_frags(blockIdx.x);

    for (int t = 0; t < TILES_PER_BLOCK; ++t) {
        const int g    = t * PERS_BLOCKS + blockIdx.x;   // iteration-major
        const int bh   = g >> 8, rem = g & 255;
        const int trow = rem >> 4, tcol = rem & 15;
        const int h    = bh % NH;
        const int brow0 = trow * 128, bcol0 = tcol * 128;

        // ---- MFMA ----
        f32x4 acc[4][4];
#pragma unroll
        for (int i = 0; i < 4; ++i)
#pragma unroll
            for (int j = 0; j < 4; ++j)
                acc[i][j] = (f32x4){0.f, 0.f, 0.f, 0.f};
#pragma unroll
        for (int kk = 0; kk < 2; ++kk)
#pragma unroll
            for (int i = 0; i < 4; ++i)
#pragma unroll
                for (int j = 0; j < 4; ++j)
                    acc[i][j] = __builtin_amdgcn_mfma_f32_16x16x32_bf16(
                        bfr[kk][j], afr[kk][i], acc[i][j], 0, 0, 0);

        // ---- in-register decay: 7 shared windows T[d], d = j-i+3 ----
        // window element w: dx = (d-3)*16 + kg*4 - r16 + w, dy wave-uniform
        {
            float w  = weight[h];
            float lw = w > 0.f ? w : 0.01f * w;
            float scale = -lw * 1.44269504088896f;
            float fdy = (float)(2 * (tcol - trow) + (wc - wr));
            float dy2 = fdy * fdy;
            f32x4 T[7];
#pragma unroll
            for (int d = 0; d < 7; ++d) {
                float dx0 = (float)((d - 3) * 16 + kg * 4 - r16);
#pragma unroll
                for (int w_ = 0; w_ < 4; ++w_) {
                    float dx = dx0 + (float)w_;
                    float dist = __builtin_amdgcn_sqrtf(dx * dx + dy2);
                    T[d][w_] = __builtin_amdgcn_exp2f(scale * dist);
                }
            }
#pragma unroll
            for (int i = 0; i < 4; ++i)
#pragma unroll
                for (int j = 0; j < 4; ++j)
                    acc[i][j] *= T[j - i + 3];
        }

        // ---- prefetch next tile's fragments BEFORE this tile's stores ----
        if (t + 1 < TILES_PER_BLOCK)
            load_frags((t + 1) * PERS_BLOCKS + blockIdx.x);
        __builtin_amdgcn_sched_barrier(0);   // keep loads above the stores

        // ---- stage to LDS (swizzled) ----
        wg_barrier_lds();                    // prev drain reads complete
#pragma unroll
        for (int i = 0; i < 4; ++i) {
            int lrow = wr * 64 + i * 16 + r16;       // 0..127
#pragma unroll
            for (int j = 0; j < 4; ++j) {
                int slot = (wc * 16 + j * 4 + kg) ^ (lrow & 7);
                *reinterpret_cast<f32x4*>(&lds[lrow * 128 + slot * 4]) = acc[i][j];
            }
        }
        wg_barrier_lds();                    // stage visible to all waves

        // ---- drain: 16 instrs/wave, each 2 rows x 512 B contiguous ----
        const size_t obase = (size_t)bh * SEQ * SEQ;
#pragma unroll
        for (int tI = 0; tI < 16; ++tI) {
            int lr = wave * 32 + tI * 2 + (lane >> 5);   // 0..127
            int slot = c32 ^ (lr & 7);
            f32x4 v = *reinterpret_cast<const f32x4*>(&lds[lr * 128 + slot * 4]);
            float* op = out + obase + (size_t)(brow0 + lr) * SEQ + bcol0 + c32 * 4;
            *reinterpret_cast<f32x4*>(op) = v;           // plain store
        }
    }
}

extern "C" void kernel_launch(void* const* d_in, const int* in_sizes, int n_in,
                              void* d_out, int out_size, void* d_ws, size_t ws_size,
                              hipStream_t stream) {
    const float* q  = (const float*)d_in[0];
    const float* b  = (const float*)d_in[1];
    const float* fr = (const float*)d_in[2];
    const float* wt = (const float*)d_in[3];
    float* out = (float*)d_out;

    const size_t need = 2 * TENSOR_ELEMS * sizeof(unsigned short);
    if (ws_size < need) return;

    rope_kernel<<<ROPE_BLOCKS, 256, 0, stream>>>(q, b, fr, (unsigned int*)d_ws);

    gemm_delta_kernel<<<PERS_BLOCKS, 256, 0, stream>>>(
        (const unsigned short*)d_ws, wt, out);
}